// Round 2
// baseline (2430.986 us; speedup 1.0000x reference)
//
#include <hip/hip_runtime.h>

#define TT 1500
#define BB 96
#define VV 128
#define LGT 256
#define LCAP 512
#define NEGF (-1.0e30f)
#define L2E 1.4426950408889634f
#define LN2F 0.6931471805599453f

// ---------------------------------------------------------------------------
// Kernel 1: greedy decode. One block per batch element.
// argmax over V per t (first-max-wins, matching jnp.argmax), then serial
// collapse (repeat/blank removal) by thread 0 out of LDS.
// ---------------------------------------------------------------------------
__global__ __launch_bounds__(256) void decode_kernel(
    const float* __restrict__ acts, const int* __restrict__ act_lens,
    int* __restrict__ dec, int* __restrict__ dec_lens) {
  __shared__ int preds[TT];
  const int b = blockIdx.x;
  const int Tl = act_lens[b];
  for (int t = threadIdx.x; t < Tl; t += 256) {
    const float4* r4 = (const float4*)(acts + ((size_t)t * BB + b) * VV);
    float best = -3.4e38f;
    int bi = 0;
#pragma unroll
    for (int i = 0; i < VV / 4; i++) {
      float4 v = r4[i];
      if (v.x > best) { best = v.x; bi = 4 * i; }
      if (v.y > best) { best = v.y; bi = 4 * i + 1; }
      if (v.z > best) { best = v.z; bi = 4 * i + 2; }
      if (v.w > best) { best = v.w; bi = 4 * i + 3; }
    }
    preds[t] = bi;
  }
  __syncthreads();
  if (threadIdx.x == 0) {
    int prev = -1;
    int cnt = 0;
    int* db = dec + (size_t)b * LCAP;
    for (int t = 0; t < Tl; t++) {
      int p = preds[t];
      if (p != 0 && p != prev) {
        if (cnt < LCAP) db[cnt] = p;
        cnt++;
      }
      prev = p;
    }
    if (cnt == 0) db[0] = 0;  // reference: zero-init buffer, dec_len clamped to >=1
    dec_lens[b] = max(1, min(cnt, LCAP));
  }
}

// ---------------------------------------------------------------------------
// Kernel 2: CTC alpha recursion on RAW acts (log-softmax shift cancels in the
// final subtraction). Base-2 log domain: alpha' = alpha*log2(e).
// Grid: 2*B blocks (even = gt, odd = hyp). 256 threads, state s = tid + 256k.
// Alphas in registers; s-1/s-2 neighbors via __shfl_up; wave boundaries via
// small double-buffered LDS edge array; acts row staged in LDS (prefetched).
// One __syncthreads per step.
// ---------------------------------------------------------------------------
__global__ __launch_bounds__(256) void ctc_kernel(
    const float* __restrict__ acts, const int* __restrict__ labels_gt,
    const int* __restrict__ act_lens, const int* __restrict__ label_lens,
    const int* __restrict__ dec, const int* __restrict__ dec_lens,
    float* __restrict__ ends) {
  const int b = blockIdx.x >> 1;
  const int hyp = blockIdx.x & 1;
  const int Tl = act_lens[b];
  const int len = hyp ? dec_lens[b] : label_lens[b];
  const int* lab = hyp ? (dec + (size_t)b * LCAP) : (labels_gt + (size_t)b * LGT);
  const int S = 2 * len + 1;
  const int KMAX = (S + 255) >> 8;  // block-uniform: #active chunks
  const int tid = threadIdx.x;
  const int lane = tid & 63, wv = tid >> 6;

  __shared__ float rowbuf[2][VV];
  __shared__ float edge[2][4][2][5];  // [parity][wave][lane62/63][chunk]
  __shared__ float fin[2];

  // Per-state static data (registers, statically indexed via full unroll).
  float alpha[5];
  int extk[5];
  bool al2[5], act_s[5];
#pragma unroll
  for (int k = 0; k < 5; k++) {
    int s = tid + (k << 8);
    bool a = s < S;
    act_s[k] = a;
    int e = 0;
    bool a2 = false;
    if (a && (s & 1)) {
      int j = s >> 1;
      e = lab[j];
      a2 = (s >= 3) && (e != 0) && (e != lab[j - 1]);
    }
    extk[k] = e;
    al2[k] = a2;
    alpha[k] = NEGF;
  }

  const float* act_b = acts + (size_t)b * VV;  // acts[(t*BB + b)*VV + v]

  // t = 0 init: alpha[0] = lp(blank), alpha[1] = lp(label0)
  if (tid == 0) alpha[0] = act_b[0] * L2E;
  if (tid == 1 && S > 1) alpha[0] = act_b[extk[0]] * L2E;

  // Prefetch row t=1 into rowbuf[1]; publish initial edges into edge[1].
  if (Tl > 1 && tid < VV) rowbuf[1][tid] = act_b[(size_t)1 * (BB * VV) + tid] * L2E;
  if (lane >= 62) {
#pragma unroll
    for (int k = 0; k < 5; k++) edge[1][wv][lane - 62][k] = alpha[k];
  }
  __syncthreads();

  for (int t = 1; t < Tl; t++) {
    const int pr = t & 1, nx = pr ^ 1;
    // stage next row (double-buffered)
    if (t + 1 < Tl && tid < VV)
      rowbuf[nx][tid] = act_b[(size_t)(t + 1) * (BB * VV) + tid] * L2E;

    // neighbor alphas from previous step (wave-wide shuffles)
    float am1[5], am2[5];
#pragma unroll
    for (int k = 0; k < 5; k++) {
      if (k < KMAX) {
        am1[k] = __shfl_up(alpha[k], 1);
        am2[k] = __shfl_up(alpha[k], 2);
      }
    }
    // fix lanes 0/1 from the edge buffer (previous wave / block wrap to k-1)
    if (lane == 0) {
      int pw = (wv == 0) ? 3 : wv - 1;
#pragma unroll
      for (int k = 0; k < 5; k++) {
        if (k < KMAX) {
          int kk = (wv == 0) ? k - 1 : k;
          am1[k] = (kk >= 0) ? edge[pr][pw][1][kk] : NEGF;
          am2[k] = (kk >= 0) ? edge[pr][pw][0][kk] : NEGF;
        }
      }
    } else if (lane == 1) {
      int pw = (wv == 0) ? 3 : wv - 1;
#pragma unroll
      for (int k = 0; k < 5; k++) {
        if (k < KMAX) {
          int kk = (wv == 0) ? k - 1 : k;
          am2[k] = (kk >= 0) ? edge[pr][pw][1][kk] : NEGF;
        }
      }
    }

    const float* rw = rowbuf[pr];
#pragma unroll
    for (int k = 0; k < 5; k++) {
      if (k < KMAX && act_s[k]) {
        int s = tid + (k << 8);
        float a0 = alpha[k];
        float a1 = (s >= 1) ? am1[k] : NEGF;
        float a2 = al2[k] ? am2[k] : NEGF;
        float m = fmaxf(fmaxf(a0, a1), a2);
        float sum = __builtin_exp2f(a0 - m) + __builtin_exp2f(a1 - m) +
                    __builtin_exp2f(a2 - m);
        alpha[k] = m + __builtin_log2f(sum) + rw[extk[k]];
      }
    }

    // publish new edges for next step
    if (lane >= 62) {
#pragma unroll
      for (int k = 0; k < 5; k++)
        if (k < KMAX) edge[nx][wv][lane - 62][k] = alpha[k];
    }
    __syncthreads();
  }

  // end = logaddexp(alpha[2*len], alpha[2*len - 1])  (base-2 domain)
#pragma unroll
  for (int k = 0; k < 5; k++) {
    int s = tid + (k << 8);
    if (s == 2 * len) fin[0] = alpha[k];
    if (s == 2 * len - 1) fin[1] = alpha[k];
  }
  __syncthreads();
  if (tid == 0) {
    float a = fin[0], c = fin[1];
    float m = fmaxf(a, c);
    float e = m + __builtin_log2f(__builtin_exp2f(a - m) + __builtin_exp2f(c - m));
    ends[hyp * BB + b] = e;
  }
}

// ---------------------------------------------------------------------------
// Kernel 3: out[b] = (end_hyp' - end_gt') * ln2 + 1.0   (lse terms cancel)
// ---------------------------------------------------------------------------
__global__ void final_kernel(const float* __restrict__ ends,
                             float* __restrict__ out) {
  int b = threadIdx.x;
  if (b < BB) out[b] = (ends[BB + b] - ends[b]) * LN2F + 1.0f;
}

extern "C" void kernel_launch(void* const* d_in, const int* in_sizes, int n_in,
                              void* d_out, int out_size, void* d_ws,
                              size_t ws_size, hipStream_t stream) {
  const float* acts = (const float*)d_in[0];
  const int* labels = (const int*)d_in[1];
  const int* act_lens = (const int*)d_in[2];
  const int* label_lens = (const int*)d_in[3];
  float* out = (float*)d_out;

  char* ws = (char*)d_ws;
  int* dec = (int*)ws;                                    // B*LCAP ints
  int* dec_lens = (int*)(ws + (size_t)BB * LCAP * 4);     // B ints
  float* ends = (float*)(ws + (size_t)BB * LCAP * 4 + BB * 4);  // 2*B floats

  decode_kernel<<<dim3(BB), dim3(256), 0, stream>>>(acts, act_lens, dec, dec_lens);
  ctc_kernel<<<dim3(2 * BB), dim3(256), 0, stream>>>(acts, labels, act_lens,
                                                     label_lens, dec, dec_lens, ends);
  final_kernel<<<dim3(1), dim3(128), 0, stream>>>(ends, out);
}

// Round 3
// 1970.210 us; speedup vs baseline: 1.2339x; 1.2339x over previous
//
#include <hip/hip_runtime.h>

#define TT 1500
#define BB 96
#define VV 128
#define LGT 256
#define LCAP 512
#define NEGF (-1.0e30f)
#define L2E 1.4426950408889634f
#define LN2F 0.6931471805599453f
#define RING 8
#define DEPTH 6

typedef const __attribute__((address_space(1))) unsigned int* gas_u32;
typedef __attribute__((address_space(3))) unsigned int* las_u32;

// ---------------------------------------------------------------------------
// Kernel 1: greedy decode. One block per batch element.
// argmax over V per t, then PARALLEL collapse: per-thread flags over 6
// contiguous t each + Hillis-Steele block scan + scatter.
// ---------------------------------------------------------------------------
__global__ __launch_bounds__(256) void decode_kernel(
    const float* __restrict__ acts, const int* __restrict__ act_lens,
    int* __restrict__ dec, int* __restrict__ dec_lens) {
  __shared__ int preds[TT];
  __shared__ int sc[256];
  const int b = blockIdx.x;
  const int tid = threadIdx.x;
  const int Tl = act_lens[b];
  for (int t = tid; t < Tl; t += 256) {
    const float4* r4 = (const float4*)(acts + ((size_t)t * BB + b) * VV);
    float best = -3.4e38f;
    int bi = 0;
#pragma unroll
    for (int i = 0; i < VV / 4; i++) {
      float4 v = r4[i];
      if (v.x > best) { best = v.x; bi = 4 * i; }
      if (v.y > best) { best = v.y; bi = 4 * i + 1; }
      if (v.z > best) { best = v.z; bi = 4 * i + 2; }
      if (v.w > best) { best = v.w; bi = 4 * i + 3; }
    }
    preds[t] = bi;
  }
  __syncthreads();

  int pv[6];
  bool fl[6];
  int cnt = 0;
#pragma unroll
  for (int j = 0; j < 6; j++) {
    int t = tid * 6 + j;
    bool valid = t < Tl;
    int p = valid ? preds[t] : 0;
    int pr = (t == 0) ? -1 : (valid ? preds[t - 1] : -1);
    bool f = valid && (p != 0) && (p != pr);
    pv[j] = p;
    fl[j] = f;
    cnt += f;
  }
  sc[tid] = cnt;
  __syncthreads();
  for (int off = 1; off < 256; off <<= 1) {
    int v = sc[tid];
    if (tid >= off) v += sc[tid - off];
    __syncthreads();
    sc[tid] = v;
    __syncthreads();
  }
  int pos = sc[tid] - cnt;  // exclusive prefix
  int total = sc[255];
  int* db = dec + (size_t)b * LCAP;
#pragma unroll
  for (int j = 0; j < 6; j++) {
    if (fl[j]) {
      if (pos < LCAP) db[pos] = pv[j];
      pos++;
    }
  }
  if (tid == 0) {
    if (total == 0) db[0] = 0;  // reference: zero buffer, dec_len clamped to >=1
    dec_lens[b] = max(1, min(total, LCAP));
  }
}

// ---------------------------------------------------------------------------
// Kernel 2: CTC alpha recursion on RAW acts (log-softmax shift cancels in the
// final gt-hyp subtraction). Base-2 log domain (L2E folded into update FMA).
// Grid: 2*B blocks (even = gt, odd = hyp), 256 threads, state s = tid + 256k.
// Deep-pipelined row staging: RING=8 LDS slots, DEPTH=6 rows in flight via
// global_load_lds; raw s_barrier with counted vmcnt(DEPTH-1) — never 0 in
// the main loop — and lgkmcnt(0) for edge-buffer visibility.
// ---------------------------------------------------------------------------
__global__ __launch_bounds__(256) void ctc_kernel(
    const float* __restrict__ acts, const int* __restrict__ labels_gt,
    const int* __restrict__ act_lens, const int* __restrict__ label_lens,
    const int* __restrict__ dec, const int* __restrict__ dec_lens,
    float* __restrict__ ends) {
  const int b = blockIdx.x >> 1;
  const int hyp = blockIdx.x & 1;
  const int Tl = act_lens[b];
  const int len = hyp ? dec_lens[b] : label_lens[b];
  const int* lab = hyp ? (dec + (size_t)b * LCAP) : (labels_gt + (size_t)b * LGT);
  const int S = 2 * len + 1;
  const int KMAX = (S + 255) >> 8;  // block-uniform chunk count
  const int tid = threadIdx.x;
  const int lane = tid & 63, wv = tid >> 6;

  __shared__ float rowbuf[RING][VV];
  __shared__ float edge[2][4][2][5];  // [parity][wave][lane62/63][chunk]
  __shared__ float fin[2];

  float alpha[5];
  int extk[5];
  bool al2[5], act_s[5];
#pragma unroll
  for (int k = 0; k < 5; k++) {
    int s = tid + (k << 8);
    bool a = s < S;
    act_s[k] = a;
    int e = 0;
    bool a2 = false;
    if (a && (s & 1)) {
      int j = s >> 1;
      e = lab[j];
      a2 = (s >= 3) && (e != 0) && (e != lab[j - 1]);
    }
    extk[k] = e;
    al2[k] = a2;
    alpha[k] = NEGF;
  }

  const float* act_b = acts + (size_t)b * VV;  // acts[(t*BB + b)*VV + v]

  // t = 0 init (direct global reads, once)
  if (tid == 0) alpha[0] = act_b[0] * L2E;
  if (tid == 1 && S > 1) alpha[0] = act_b[extk[0]] * L2E;

  // Prologue: issue rows 1..DEPTH into slots 1..DEPTH (waves 0-1 only).
  if (tid < VV) {
#pragma unroll
    for (int r = 1; r <= DEPTH; r++) {
      int rr = (r < Tl) ? r : (Tl - 1);
      const float* gp = act_b + (size_t)rr * (BB * VV) + tid;
      __builtin_amdgcn_global_load_lds((gas_u32)gp,
                                       (las_u32)&rowbuf[r & (RING - 1)][wv << 6],
                                       4, 0, 0);
    }
  }
  // Publish initial edges (parity 1 consumed at t=1).
  if (lane >= 62) {
#pragma unroll
    for (int k = 0; k < 5; k++) edge[1][wv][lane - 62][k] = alpha[k];
  }
  asm volatile("s_waitcnt vmcnt(5)" ::: "memory");  // row 1 certified
  asm volatile("s_waitcnt lgkmcnt(0)" ::: "memory");
  __builtin_amdgcn_s_barrier();

  for (int t = 1; t < Tl; t++) {
    const int pr = t & 1, nx = pr ^ 1;
    const float* rw = rowbuf[t & (RING - 1)];

    // Issue prefetch for row t+DEPTH (clamped; keeps vmcnt constant in tail)
    // into slot (t+DEPTH)&7 — that slot was last consumed at step t-2.
    if (tid < VV) {
      int rr = t + DEPTH;
      if (rr > Tl - 1) rr = Tl - 1;
      const float* gp = act_b + (size_t)rr * (BB * VV) + tid;
      __builtin_amdgcn_global_load_lds(
          (gas_u32)gp, (las_u32)&rowbuf[(t + DEPTH) & (RING - 1)][wv << 6], 4, 0, 0);
    }

    // neighbor alphas from previous step (wave-wide shuffles)
    float am1[5], am2[5];
#pragma unroll
    for (int k = 0; k < 5; k++) {
      if (k < KMAX) {
        am1[k] = __shfl_up(alpha[k], 1);
        am2[k] = __shfl_up(alpha[k], 2);
      }
    }
    // fix lanes 0/1 from the edge buffer (previous wave / chunk wrap)
    if (lane == 0) {
      int pw = (wv == 0) ? 3 : wv - 1;
#pragma unroll
      for (int k = 0; k < 5; k++) {
        if (k < KMAX) {
          int kk = (wv == 0) ? k - 1 : k;
          am1[k] = (kk >= 0) ? edge[pr][pw][1][kk] : NEGF;
          am2[k] = (kk >= 0) ? edge[pr][pw][0][kk] : NEGF;
        }
      }
    } else if (lane == 1) {
      int pw = (wv == 0) ? 3 : wv - 1;
#pragma unroll
      for (int k = 0; k < 5; k++) {
        if (k < KMAX) {
          int kk = (wv == 0) ? k - 1 : k;
          am2[k] = (kk >= 0) ? edge[pr][pw][1][kk] : NEGF;
        }
      }
    }

#pragma unroll
    for (int k = 0; k < 5; k++) {
      if (k < KMAX && act_s[k]) {
        int s = tid + (k << 8);
        float a0 = alpha[k];
        float a1 = (s >= 1) ? am1[k] : NEGF;
        float a2 = al2[k] ? am2[k] : NEGF;
        float m = fmaxf(fmaxf(a0, a1), a2);
        float sum = __builtin_exp2f(a0 - m) + __builtin_exp2f(a1 - m) +
                    __builtin_exp2f(a2 - m);
        alpha[k] = __builtin_fmaf(rw[extk[k]], L2E, m + __builtin_log2f(sum));
      }
    }

    // publish new edges for next step
    if (lane >= 62) {
#pragma unroll
      for (int k = 0; k < 5; k++)
        if (k < KMAX) edge[nx][wv][lane - 62][k] = alpha[k];
    }
    asm volatile("s_waitcnt vmcnt(5)" ::: "memory");  // row t+1 certified
    asm volatile("s_waitcnt lgkmcnt(0)" ::: "memory");  // edges visible
    __builtin_amdgcn_s_barrier();
  }

  // end = logaddexp(alpha[2*len], alpha[2*len - 1])  (base-2 domain)
#pragma unroll
  for (int k = 0; k < 5; k++) {
    int s = tid + (k << 8);
    if (s == 2 * len) fin[0] = alpha[k];
    if (s == 2 * len - 1) fin[1] = alpha[k];
  }
  __syncthreads();
  if (tid == 0) {
    float a = fin[0], c = fin[1];
    float m = fmaxf(a, c);
    float e = m + __builtin_log2f(__builtin_exp2f(a - m) + __builtin_exp2f(c - m));
    ends[hyp * BB + b] = e;
  }
}

// ---------------------------------------------------------------------------
// Kernel 3: out[b] = (end_hyp' - end_gt') * ln2 + 1.0   (lse terms cancel)
// ---------------------------------------------------------------------------
__global__ void final_kernel(const float* __restrict__ ends,
                             float* __restrict__ out) {
  int b = threadIdx.x;
  if (b < BB) out[b] = (ends[BB + b] - ends[b]) * LN2F + 1.0f;
}

extern "C" void kernel_launch(void* const* d_in, const int* in_sizes, int n_in,
                              void* d_out, int out_size, void* d_ws,
                              size_t ws_size, hipStream_t stream) {
  const float* acts = (const float*)d_in[0];
  const int* labels = (const int*)d_in[1];
  const int* act_lens = (const int*)d_in[2];
  const int* label_lens = (const int*)d_in[3];
  float* out = (float*)d_out;

  char* ws = (char*)d_ws;
  int* dec = (int*)ws;                                          // B*LCAP ints
  int* dec_lens = (int*)(ws + (size_t)BB * LCAP * 4);           // B ints
  float* ends = (float*)(ws + (size_t)BB * LCAP * 4 + BB * 4);  // 2*B floats

  decode_kernel<<<dim3(BB), dim3(256), 0, stream>>>(acts, act_lens, dec, dec_lens);
  ctc_kernel<<<dim3(2 * BB), dim3(256), 0, stream>>>(acts, labels, act_lens,
                                                     label_lens, dec, dec_lens, ends);
  final_kernel<<<dim3(1), dim3(128), 0, stream>>>(ends, out);
}

// Round 4
// 1352.124 us; speedup vs baseline: 1.7979x; 1.4571x over previous
//
#include <hip/hip_runtime.h>

#define TT 1500
#define BB 96
#define VV 128
#define LGT 256
#define LCAP 512
#define NEGF (-1.0e30f)
#define L2E 1.4426950408889634f
#define LN2F 0.6931471805599453f
#define MAXC 5   // max processed chunks/wave (hyp CT=17 -> 5)
#define HREF 30  // ghost refresh cadence; 2*HREF=60 < 64-state ghost chunk

// ---------------------------------------------------------------------------
// Kernel 1: greedy decode (unchanged from round 3).
// ---------------------------------------------------------------------------
__global__ __launch_bounds__(256) void decode_kernel(
    const float* __restrict__ acts, const int* __restrict__ act_lens,
    int* __restrict__ dec, int* __restrict__ dec_lens) {
  __shared__ int preds[TT];
  __shared__ int sc[256];
  const int b = blockIdx.x;
  const int tid = threadIdx.x;
  const int Tl = act_lens[b];
  for (int t = tid; t < Tl; t += 256) {
    const float4* r4 = (const float4*)(acts + ((size_t)t * BB + b) * VV);
    float best = -3.4e38f;
    int bi = 0;
#pragma unroll
    for (int i = 0; i < VV / 4; i++) {
      float4 v = r4[i];
      if (v.x > best) { best = v.x; bi = 4 * i; }
      if (v.y > best) { best = v.y; bi = 4 * i + 1; }
      if (v.z > best) { best = v.z; bi = 4 * i + 2; }
      if (v.w > best) { best = v.w; bi = 4 * i + 3; }
    }
    preds[t] = bi;
  }
  __syncthreads();

  int pv[6];
  bool fl[6];
  int cnt = 0;
#pragma unroll
  for (int j = 0; j < 6; j++) {
    int t = tid * 6 + j;
    bool valid = t < Tl;
    int p = valid ? preds[t] : 0;
    int pr = (t == 0) ? -1 : (valid ? preds[t - 1] : -1);
    bool f = valid && (p != 0) && (p != pr);
    pv[j] = p;
    fl[j] = f;
    cnt += f;
  }
  sc[tid] = cnt;
  __syncthreads();
  for (int off = 1; off < 256; off <<= 1) {
    int v = sc[tid];
    if (tid >= off) v += sc[tid - off];
    __syncthreads();
    sc[tid] = v;
    __syncthreads();
  }
  int pos = sc[tid] - cnt;  // exclusive prefix
  int total = sc[255];
  int* db = dec + (size_t)b * LCAP;
#pragma unroll
  for (int j = 0; j < 6; j++) {
    if (fl[j]) {
      if (pos < LCAP) db[pos] = pv[j];
      pos++;
    }
  }
  if (tid == 0) {
    if (total == 0) db[0] = 0;
    dec_lens[b] = max(1, min(total, LCAP));
  }
}

// ---------------------------------------------------------------------------
// Kernel 2: CTC on raw acts, ghost-zone decomposition.
// 4 waves/block; wave w owns a contiguous chunk span + 1 ghost chunk below.
// Main loop: NO barriers, NO LDS — intra-wave rotate-shuffles + register
// prefetch (3-deep) of per-state logit gathers from global. Cross-wave
// ghost refresh via LDS every HREF=30 steps (error front moves 2 states/step,
// 2*30 < 64 = ghost size).
// ---------------------------------------------------------------------------
#define GSTEP(G)                                                           \
  {                                                                        \
    float r1[MAXC], r2[MAXC];                                              \
    _Pragma("unroll") for (int j = 0; j < MAXC; j++) if (j < pcN) {        \
      r1[j] = __shfl(alpha[j], lm1);                                       \
      r2[j] = __shfl(alpha[j], lm2);                                       \
    }                                                                      \
    _Pragma("unroll") for (int j = 0; j < MAXC; j++) if (j < pcN) {        \
      float a0 = alpha[j];                                                 \
      float a1 = (lane == 0) ? ((j > 0) ? r1[j - 1] : NEGF) : r1[j];       \
      float p2 = (j > 0) ? r2[j - 1] : NEGF;                               \
      float a2 = al2[j] ? ((lane < 2) ? p2 : r2[j]) : NEGF;                \
      float m = fmaxf(fmaxf(a0, a1), a2);                                  \
      float sm = __builtin_exp2f(a0 - m) + __builtin_exp2f(a1 - m) +       \
                 __builtin_exp2f(a2 - m);                                  \
      alpha[j] = __builtin_fmaf(G[j], L2E, m + __builtin_log2f(sm));       \
    }                                                                      \
  }

#define GPREF(G, ROW)                                                      \
  {                                                                        \
    const float* rp = act_b + (size_t)(ROW) * (BB * VV);                   \
    _Pragma("unroll") for (int j = 0; j < MAXC; j++) if (j < pcN)          \
        G[j] = rp[extk[j]];                                                \
  }

#define REFRESH()                                                          \
  {                                                                        \
    __syncthreads();                                                       \
    _Pragma("unroll") for (int j = 0; j < MAXC; j++) if (j < pcN) {        \
      int gc = pc0 + j;                                                    \
      if (gc >= ow0) xall[gc][lane] = alpha[j];                            \
    }                                                                      \
    __syncthreads();                                                       \
    if (wv > 0 && pcN > 0) alpha[0] = xall[pc0][lane];                     \
  }

__global__ __launch_bounds__(256) void ctc_kernel(
    const float* __restrict__ acts, const int* __restrict__ labels_gt,
    const int* __restrict__ act_lens, const int* __restrict__ label_lens,
    const int* __restrict__ dec, const int* __restrict__ dec_lens,
    float* __restrict__ ends) {
  const int b = blockIdx.x >> 1;
  const int hyp = blockIdx.x & 1;
  const int Tl = act_lens[b];
  const int len = hyp ? dec_lens[b] : label_lens[b];
  const int* lab = hyp ? (dec + (size_t)b * LCAP) : (labels_gt + (size_t)b * LGT);
  const int S = 2 * len + 1;
  const int CT = (S + 63) >> 6;  // total 64-state chunks (<= 17)
  const int tid = threadIdx.x;
  const int lane = tid & 63, wv = tid >> 6;
  const int lm1 = (lane + 63) & 63, lm2 = (lane + 62) & 63;

  // chunk partition: wave w owns [ow0, ow1), processes [pc0, pc0+pcN)
  const int q = CT >> 2, r = CT & 3;
  const int ow0 = wv * q + (wv < r ? wv : r);
  const int ow1 = ow0 + q + (wv < r ? 1 : 0);
  const int pc0 = (wv == 0) ? 0 : (ow0 - 1);
  const int pcN = ow1 - pc0;  // <= 5; may be <=1 for idle waves (harmless)

  __shared__ float xall[17][64];
  __shared__ float fin[2];

  float alpha[MAXC];
  int extk[MAXC];
  bool al2[MAXC];
#pragma unroll
  for (int j = 0; j < MAXC; j++) {
    alpha[j] = NEGF;
    extk[j] = 0;
    al2[j] = false;
    if (j < pcN) {
      int s = ((pc0 + j) << 6) + lane;
      if (s < S && (s & 1)) {
        int i = s >> 1;
        int e = lab[i];
        extk[j] = e;
        al2[j] = (s >= 3) && (e != 0) && (e != lab[i - 1]);
      }
    }
  }

  const float* act_b = acts + (size_t)b * VV;  // acts[(t*BB + b)*VV + v]

  // t = 0 init (states 0 and 1 live in wave 0, chunk 0)
  if (tid == 0) alpha[0] = act_b[0] * L2E;
  if (tid == 1 && S > 1) alpha[0] = act_b[extk[0]] * L2E;

  // 3-deep register prefetch of per-state logit gathers
  float gA[MAXC], gB[MAXC], gC[MAXC];
  {
    int r1_ = (1 < Tl) ? 1 : Tl - 1;
    int r2_ = (2 < Tl) ? 2 : Tl - 1;
    int r3_ = (3 < Tl) ? 3 : Tl - 1;
    GPREF(gA, r1_);
    GPREF(gB, r2_);
    GPREF(gC, r3_);
  }

  int t = 1, since = 0;
  while (t < Tl) {
    GSTEP(gA);
    { int nr = t + 3; if (nr > Tl - 1) nr = Tl - 1; GPREF(gA, nr); }
    ++t; ++since;
    if (since >= HREF) { if (t < Tl) REFRESH(); since = 0; }
    if (t >= Tl) break;

    GSTEP(gB);
    { int nr = t + 3; if (nr > Tl - 1) nr = Tl - 1; GPREF(gB, nr); }
    ++t; ++since;
    if (since >= HREF) { if (t < Tl) REFRESH(); since = 0; }
    if (t >= Tl) break;

    GSTEP(gC);
    { int nr = t + 3; if (nr > Tl - 1) nr = Tl - 1; GPREF(gC, nr); }
    ++t; ++since;
    if (since >= HREF) { if (t < Tl) REFRESH(); since = 0; }
  }

  // end = logaddexp(alpha[2*len], alpha[2*len-1]) from OWNED chunks only
  __syncthreads();
#pragma unroll
  for (int j = 0; j < MAXC; j++) {
    if (j < pcN) {
      int gc = pc0 + j;
      if (gc >= ow0) {
        int s = (gc << 6) + lane;
        if (s == 2 * len) fin[0] = alpha[j];
        if (s == 2 * len - 1) fin[1] = alpha[j];
      }
    }
  }
  __syncthreads();
  if (tid == 0) {
    float a = fin[0], c = fin[1];
    float m = fmaxf(a, c);
    float e = m + __builtin_log2f(__builtin_exp2f(a - m) + __builtin_exp2f(c - m));
    ends[hyp * BB + b] = e;
  }
}

// ---------------------------------------------------------------------------
// Kernel 3: out[b] = (end_hyp' - end_gt') * ln2 + 1.0   (lse terms cancel)
// ---------------------------------------------------------------------------
__global__ void final_kernel(const float* __restrict__ ends,
                             float* __restrict__ out) {
  int b = threadIdx.x;
  if (b < BB) out[b] = (ends[BB + b] - ends[b]) * LN2F + 1.0f;
}

extern "C" void kernel_launch(void* const* d_in, const int* in_sizes, int n_in,
                              void* d_out, int out_size, void* d_ws,
                              size_t ws_size, hipStream_t stream) {
  const float* acts = (const float*)d_in[0];
  const int* labels = (const int*)d_in[1];
  const int* act_lens = (const int*)d_in[2];
  const int* label_lens = (const int*)d_in[3];
  float* out = (float*)d_out;

  char* ws = (char*)d_ws;
  int* dec = (int*)ws;                                          // B*LCAP ints
  int* dec_lens = (int*)(ws + (size_t)BB * LCAP * 4);           // B ints
  float* ends = (float*)(ws + (size_t)BB * LCAP * 4 + BB * 4);  // 2*B floats

  decode_kernel<<<dim3(BB), dim3(256), 0, stream>>>(acts, act_lens, dec, dec_lens);
  ctc_kernel<<<dim3(2 * BB), dim3(256), 0, stream>>>(acts, labels, act_lens,
                                                     label_lens, dec, dec_lens, ends);
  final_kernel<<<dim3(1), dim3(128), 0, stream>>>(ends, out);
}

// Round 5
// 708.751 us; speedup vs baseline: 3.4300x; 1.9078x over previous
//
#include <hip/hip_runtime.h>

#define TT 1500
#define BB 96
#define VV 128
#define LGT 256
#define LCAP 512
#define NEGF (-1.0e30f)
#define L2E 1.4426950408889634f
#define LN2F 0.6931471805599453f
#define HREF 30  // refresh cadence: 2*HREF=60 < 63-state ghost

// ---------------------------------------------------------------------------
// Kernel 1: greedy decode (unchanged).
// ---------------------------------------------------------------------------
__global__ __launch_bounds__(256) void decode_kernel(
    const float* __restrict__ acts, const int* __restrict__ act_lens,
    int* __restrict__ dec, int* __restrict__ dec_lens) {
  __shared__ int preds[TT];
  __shared__ int sc[256];
  const int b = blockIdx.x;
  const int tid = threadIdx.x;
  const int Tl = act_lens[b];
  for (int t = tid; t < Tl; t += 256) {
    const float4* r4 = (const float4*)(acts + ((size_t)t * BB + b) * VV);
    float best = -3.4e38f;
    int bi = 0;
#pragma unroll
    for (int i = 0; i < VV / 4; i++) {
      float4 v = r4[i];
      if (v.x > best) { best = v.x; bi = 4 * i; }
      if (v.y > best) { best = v.y; bi = 4 * i + 1; }
      if (v.z > best) { best = v.z; bi = 4 * i + 2; }
      if (v.w > best) { best = v.w; bi = 4 * i + 3; }
    }
    preds[t] = bi;
  }
  __syncthreads();

  int pv[6];
  bool fl[6];
  int cnt = 0;
#pragma unroll
  for (int j = 0; j < 6; j++) {
    int t = tid * 6 + j;
    bool valid = t < Tl;
    int p = valid ? preds[t] : 0;
    int pr = (t == 0) ? -1 : (valid ? preds[t - 1] : -1);
    bool f = valid && (p != 0) && (p != pr);
    pv[j] = p;
    fl[j] = f;
    cnt += f;
  }
  sc[tid] = cnt;
  __syncthreads();
  for (int off = 1; off < 256; off <<= 1) {
    int v = sc[tid];
    if (tid >= off) v += sc[tid - off];
    __syncthreads();
    sc[tid] = v;
    __syncthreads();
  }
  int pos = sc[tid] - cnt;  // exclusive prefix
  int total = sc[255];
  int* db = dec + (size_t)b * LCAP;
#pragma unroll
  for (int j = 0; j < 6; j++) {
    if (fl[j]) {
      if (pos < LCAP) db[pos] = pv[j];
      pos++;
    }
  }
  if (tid == 0) {
    if (total == 0) db[0] = 0;
    dec_lens[b] = max(1, min(total, LCAP));
  }
}

// ---------------------------------------------------------------------------
// Kernel 2: CTC on raw acts. LANE-MAJOR layout: lane l holds R consecutive
// states [p0 + l*R, p0 + l*R + R) in registers. s-1/s-2 for r>=2 are
// register-local; only r=0,1 need prev lane's top two regs -> 2 bpermutes
// per step (issued first, hidden under the register-only r>=2 updates).
// Wave w owns states [w*oS, (w+1)*oS); processes a 63-state ghost below;
// cross-wave refresh via LDS every HREF=30 steps. Gather prefetch: 4-buffer
// rotation, pref issued at step top (3 steps of latency cover).
// ---------------------------------------------------------------------------
template <int R>
__device__ void ctc_core(const float* __restrict__ act_b,
                         const int* __restrict__ lab, int Tl, int len, int S,
                         float* __restrict__ xall, float* __restrict__ fin,
                         float* __restrict__ ends, int outIdx) {
  const int tid = threadIdx.x;
  const int lane = tid & 63, wv = tid >> 6;
  const int lm1 = (lane + 63) & 63;
  const int oS = (S + 3) >> 2;          // owned span per wave
  const int o0 = min(wv * oS, S);
  const int o1 = min(o0 + oS, S);
  const int p0 = max(0, o0 - 63);       // processed-span bottom (ghost below owned)

  float alpha[R];
  float g0[R], g1[R], g2[R], g3[R];
  int extk[R];
  bool al2[R];
  int sst[R];
#pragma unroll
  for (int r = 0; r < R; r++) {
    int s = p0 + lane * R + r;
    sst[r] = s;
    alpha[r] = NEGF;
    extk[r] = 0;
    al2[r] = false;
    if (s < S && (s & 1)) {
      int i = s >> 1;
      int e = lab[i];
      extk[r] = e;
      al2[r] = (s >= 3) && (e != 0) && (e != lab[i - 1]);
    }
  }
  // t = 0 init: states 0,1 live in wave 0, lane 0, regs 0,1 (R >= 2 always)
  if (wv == 0 && lane == 0) {
    alpha[0] = act_b[0] * L2E;
    alpha[1] = act_b[extk[1]] * L2E;
  }

  auto pref = [&](float* G, int row) {
    const float* rp = act_b + (size_t)row * (BB * VV);
#pragma unroll
    for (int r = 0; r < R; r++) G[r] = rp[extk[r]];
  };
  auto lse3 = [](float a0, float a1, float a2) {
    float m = fmaxf(fmaxf(a0, a1), a2);
    float sm = __builtin_exp2f(a0 - m) + __builtin_exp2f(a1 - m) +
               __builtin_exp2f(a2 - m);
    return m + __builtin_log2f(sm);
  };
  auto step = [&](const float* G) {
    // prev lane's top two states (s-1, s-2 for this lane's r=0)
    float pT1 = __shfl(alpha[R - 1], lm1);
    float pT2 = __shfl(alpha[R - 2], lm1);
    // r >= 2: fully register-local; all updates read previous-step values
    // (top-down order keeps r-1, r-2 un-updated when read).
#pragma unroll
    for (int r = R - 1; r >= 2; r--) {
      float a2 = al2[r] ? alpha[r - 2] : NEGF;
      alpha[r] = __builtin_fmaf(G[r], L2E, lse3(alpha[r], alpha[r - 1], a2));
    }
    {
      float a2 = (al2[1] && lane != 0) ? pT1 : NEGF;
      alpha[1] = __builtin_fmaf(G[1], L2E, lse3(alpha[1], alpha[0], a2));
    }
    {
      float a1 = (lane != 0) ? pT1 : NEGF;
      float a2 = (al2[0] && lane != 0) ? pT2 : NEGF;
      alpha[0] = __builtin_fmaf(G[0], L2E, lse3(alpha[0], a1, a2));
    }
  };
  auto refresh = [&]() {
    __syncthreads();
#pragma unroll
    for (int r = 0; r < R; r++)
      if (sst[r] >= o0 && sst[r] < o1) xall[sst[r]] = alpha[r];
    __syncthreads();
#pragma unroll
    for (int r = 0; r < R; r++)
      if (sst[r] < o0) alpha[r] = xall[sst[r]];  // ghost reload (sst >= p0 >= 0)
  };

  pref(g1, min(1, Tl - 1));
  pref(g2, min(2, Tl - 1));
  pref(g3, min(3, Tl - 1));

#define STAGE(PG, UG)                                        \
  pref(PG, min(t + 3, Tl - 1));                              \
  step(UG);                                                  \
  ++t;                                                       \
  if (++since >= HREF) {                                     \
    if (t < Tl) refresh();                                   \
    since = 0;                                               \
  }                                                          \
  if (t >= Tl) break;

  int t = 1, since = 0;
  while (t < Tl) {
    STAGE(g0, g1)
    STAGE(g1, g2)
    STAGE(g2, g3)
    STAGE(g3, g0)
  }
#undef STAGE

  // end = logaddexp(alpha[2*len], alpha[2*len-1]) from owned states
  __syncthreads();
#pragma unroll
  for (int r = 0; r < R; r++) {
    if (sst[r] >= o0 && sst[r] < o1) {
      if (sst[r] == 2 * len) fin[0] = alpha[r];
      if (sst[r] == 2 * len - 1) fin[1] = alpha[r];
    }
  }
  __syncthreads();
  if (tid == 0) {
    float a = fin[0], c = fin[1];
    float m = fmaxf(a, c);
    float e = m + __builtin_log2f(__builtin_exp2f(a - m) + __builtin_exp2f(c - m));
    ends[outIdx] = e;
  }
}

__global__ __launch_bounds__(256, 1) void ctc_kernel(
    const float* __restrict__ acts, const int* __restrict__ labels_gt,
    const int* __restrict__ act_lens, const int* __restrict__ label_lens,
    const int* __restrict__ dec, const int* __restrict__ dec_lens,
    float* __restrict__ ends) {
  __shared__ float xall[2 * LCAP + 1];
  __shared__ float fin[2];
  const int b = blockIdx.x >> 1;
  const int hyp = blockIdx.x & 1;
  const int Tl = act_lens[b];
  const int len = hyp ? dec_lens[b] : label_lens[b];
  const int* lab = hyp ? (dec + (size_t)b * LCAP) : (labels_gt + (size_t)b * LGT);
  const int S = 2 * len + 1;
  const float* act_b = acts + (size_t)b * VV;  // acts[(t*BB + b)*VV + v]
  const int oS = (S + 3) >> 2;
  int Rd = (oS + 126) >> 6;  // ceil((oS+63)/64)
  if (Rd < 2) Rd = 2;
  const int oi = hyp * BB + b;
  if (Rd == 2)
    ctc_core<2>(act_b, lab, Tl, len, S, xall, fin, ends, oi);
  else if (Rd == 3)
    ctc_core<3>(act_b, lab, Tl, len, S, xall, fin, ends, oi);
  else if (Rd == 4)
    ctc_core<4>(act_b, lab, Tl, len, S, xall, fin, ends, oi);
  else
    ctc_core<5>(act_b, lab, Tl, len, S, xall, fin, ends, oi);
}

// ---------------------------------------------------------------------------
// Kernel 3: out[b] = (end_hyp' - end_gt') * ln2 + 1.0   (lse terms cancel)
// ---------------------------------------------------------------------------
__global__ void final_kernel(const float* __restrict__ ends,
                             float* __restrict__ out) {
  int b = threadIdx.x;
  if (b < BB) out[b] = (ends[BB + b] - ends[b]) * LN2F + 1.0f;
}

extern "C" void kernel_launch(void* const* d_in, const int* in_sizes, int n_in,
                              void* d_out, int out_size, void* d_ws,
                              size_t ws_size, hipStream_t stream) {
  const float* acts = (const float*)d_in[0];
  const int* labels = (const int*)d_in[1];
  const int* act_lens = (const int*)d_in[2];
  const int* label_lens = (const int*)d_in[3];
  float* out = (float*)d_out;

  char* ws = (char*)d_ws;
  int* dec = (int*)ws;                                          // B*LCAP ints
  int* dec_lens = (int*)(ws + (size_t)BB * LCAP * 4);           // B ints
  float* ends = (float*)(ws + (size_t)BB * LCAP * 4 + BB * 4);  // 2*B floats

  decode_kernel<<<dim3(BB), dim3(256), 0, stream>>>(acts, act_lens, dec, dec_lens);
  ctc_kernel<<<dim3(2 * BB), dim3(256), 0, stream>>>(acts, labels, act_lens,
                                                     label_lens, dec, dec_lens, ends);
  final_kernel<<<dim3(1), dim3(128), 0, stream>>>(ends, out);
}